// Round 7
// baseline (24.153 us; speedup 1.0000x reference)
//
#include <hip/hip_runtime.h>

#define NEG (-1e6f)

static constexpr int B = 32, Q = 64, K = 512, H = 64, V = 64;
static constexpr float C2LE = 2.8853900817779268f;   // 2*log2(e)
static constexpr float L2E  = 1.4426950408889634f;   // log2(e)

typedef __attribute__((ext_vector_type(8))) short bf16x8;
typedef __attribute__((ext_vector_type(4))) float f32x4;

__device__ __forceinline__ float fexp2(float x) { return __builtin_amdgcn_exp2f(x); }
__device__ __forceinline__ float frcp(float x)  { return __builtin_amdgcn_rcpf(x); }

__device__ __forceinline__ unsigned short f2bf(float f) {  // RNE f32 -> bf16
  union { float f; unsigned u; } v; v.f = f;
  unsigned r = v.u + 0x7fffu + ((v.u >> 16) & 1u);
  return (unsigned short)(r >> 16);
}
__device__ __forceinline__ unsigned pack2bf(float lo, float hi) {
  return (unsigned)f2bf(lo) | ((unsigned)f2bf(hi) << 16);
}

// ---- MFMA projections + fused exponentials, vlen-skipped, XCD-affine.
// Grid 288 = 8 XCDs x 36 slots. Slot 0..3: q-block of b=xcd*4+slot.
// Slot 4..35: key chunk, b = xcd*4 + (idx&3) (b fastest -> mixed vlen per CU),
// kb64 = idx>>2. All data for batch b produced on XCD b>>2.
// Query rows -> qAR2[(((b*32+qg)*32+hp)*8) + qi*4 + (h&1)*2 + {A,R}]
//   (per (b,qg=q>>1): 256 contiguous dwords; 8 dwords per hp -> s_load_dwordx8)
//   A = -2*wv_h*e^{-2q}, R = e^{-2q}
// Key rows   -> Ekp[b][hp][k] = {bf16(e^{2k_h0}), bf16(e^{2k_h1})} packed dword.
// wv_h*tanh(q+k) = wv_h + A*rcp(R+E); const sum(wv) dropped (softmax shift-inv).
// Clamp +-15 pre-exp (tanh saturated). MFMA 16x16x32 bf16 (m89/m91 layout);
// swapped operands transpose D so key tiles come out h-major.
__global__ __launch_bounds__(256) void proj_kernel(
    const float* __restrict__ queries, const float* __restrict__ keys,
    const float* __restrict__ Wq, const float* __restrict__ Wk,
    const float* __restrict__ wv, const int* __restrict__ vlens,
    float* __restrict__ qAR2, unsigned* __restrict__ Ekp)
{
  __shared__ float Wl[64 * 65];                    // +1 pad: <=2-way (free)
  const int xcd = blockIdx.x & 7, slot = blockIdx.x >> 3;
  const bool isQ = slot < 4;                       // block-uniform
  const int idx = slot - 4;
  const int b = isQ ? (xcd * 4 + slot) : (xcd * 4 + (idx & 3));
  const int kb64 = idx >> 2;
  const int vlen = vlens[b];
  if (!isQ && kb64 * 64 >= vlen) return;           // whole chunk masked

  const int tid = threadIdx.x, lane = tid & 63;
  const int wave = __builtin_amdgcn_readfirstlane(tid >> 6);
  const float* Wsrc = isQ ? Wq : Wk;
  #pragma unroll
  for (int i = 0; i < 16; ++i) {                   // stage W (coalesced)
    const int j = tid + i * 256;
    Wl[(j >> 6) * 65 + (j & 63)] = Wsrc[j];
  }
  __syncthreads();

  const int r = lane & 15, g = lane >> 4;
  const int rloc0 = (isQ ? 0 : kb64 * 64) + wave * 16;   // row-in-b of stripe
  if (!isQ && rloc0 >= vlen) return;               // after the only barrier
  const float* xbase = isQ ? (queries + ((size_t)b * Q + rloc0) * H)
                           : (keys    + ((size_t)b * K + rloc0) * H);

  bf16x8 afr[2];
  #pragma unroll
  for (int kb = 0; kb < 2; ++kb) {                 // X frag: 8 contiguous k/lane
    const float* px = xbase + (size_t)r * H + kb * 32 + g * 8;
    const float4 x0 = *(const float4*)px;
    const float4 x1 = *(const float4*)(px + 4);
    bf16x8 a;
    a[0]=(short)f2bf(x0.x); a[1]=(short)f2bf(x0.y); a[2]=(short)f2bf(x0.z); a[3]=(short)f2bf(x0.w);
    a[4]=(short)f2bf(x1.x); a[5]=(short)f2bf(x1.y); a[6]=(short)f2bf(x1.z); a[7]=(short)f2bf(x1.w);
    afr[kb] = a;
  }

  #pragma unroll
  for (int t = 0; t < 4; ++t) {                    // 4 h-tiles of 16
    const int hcol = t * 16 + r;
    f32x4 acc = {0.f, 0.f, 0.f, 0.f};
    #pragma unroll
    for (int kb = 0; kb < 2; ++kb) {
      bf16x8 wfr;
      #pragma unroll
      for (int j = 0; j < 8; ++j)
        wfr[j] = (short)f2bf(Wl[(kb*32 + g*8 + j) * 65 + hcol]);
      acc = isQ ? __builtin_amdgcn_mfma_f32_16x16x32_bf16(afr[kb], wfr, acc, 0, 0, 0)
                : __builtin_amdgcn_mfma_f32_16x16x32_bf16(wfr, afr[kb], acc, 0, 0, 0);
    }
    if (isQ) {
      // D: col(=h)=r, row(=q-row)=g*4+reg
      const float wvv = wv[hcol];
      #pragma unroll
      for (int rr = 0; rr < 4; ++rr) {
        const int qq = rloc0 + g * 4 + rr;
        const float s = fminf(15.f, fmaxf(-15.f, acc[rr])) * C2LE;
        const float rq = fexp2(-s);
        const size_t off = (((size_t)(b * 32 + (qq >> 1)) * 32 + (hcol >> 1)) * 8)
                           + (qq & 1) * 4 + (hcol & 1) * 2;
        *(float2*)(qAR2 + off) = make_float2(-2.f * wvv * rq, rq);
      }
    } else {
      // D transposed: col(=k)=r, row(=h)=t*16+g*4+reg; pack h-pairs as bf16x2
      const int k = rloc0 + r;
      float E[4];
      #pragma unroll
      for (int rr = 0; rr < 4; ++rr)
        E[rr] = fexp2(fminf(15.f, fmaxf(-15.f, acc[rr])) * C2LE);
      const int hp = t * 8 + g * 2;
      Ekp[((size_t)b*32 + hp    ) * 512 + k] = pack2bf(E[0], E[1]);
      Ekp[((size_t)b*32 + hp + 1) * 512 + k] = pack2bf(E[2], E[3]);
    }
  }
}

// ---- fused attention: grid 1024 = 8 XCDs x 128 slots; block=(b, 2 queries),
// 512 threads = 8 waves, 4 blocks/CU -> 8 waves/SIMD. b varies fastest within
// an XCD so co-resident blocks have mixed vlens (balance); XCD b>>2 matches
// the producer (L2 affinity). Score phase: thread=key; ALL 32 Ekp dwords
// batch-prefetched to VGPRs (one vmcnt drain), A/R via s_load_dwordx8 per hp;
// inner loop is pure VALU/trans. Waves fully past vlen skip phases 1 & 3.
__global__ __launch_bounds__(512) void attn_kernel(
    const float* __restrict__ qAR2, const unsigned* __restrict__ Ekp,
    const float* __restrict__ values, const int* __restrict__ vlens,
    float* __restrict__ out)
{
  __shared__ float p[2][K];          // 4KB: scores -> probs
  __shared__ float part[8][2][V];    // 4KB: PV partials
  __shared__ float red[2][4][2];     // [query][quarter][max,sum]

  const int xcd = blockIdx.x & 7, slot = blockIdx.x >> 3;
  const int b = xcd * 4 + (slot & 3), qg = slot >> 2;    // qg in [0,32)
  const int vlen = vlens[b];
  const int tid = threadIdx.x, lane = tid & 63;
  const int wave = __builtin_amdgcn_readfirstlane(tid >> 6);

  // ---- phase 1: scores, thread = key tid; skip waves fully past vlen
  if (wave * 64 < vlen) {
    const unsigned* ekp = Ekp + (size_t)b * 32 * 512 + tid;
    const float* ar = qAR2 +
        (size_t)__builtin_amdgcn_readfirstlane((b * 32 + qg) * 256);
    unsigned ek[32];
    #pragma unroll
    for (int hp = 0; hp < 32; ++hp) ek[hp] = ekp[hp * 512];  // batch prefetch
    float a0 = 0.f, a1 = 0.f;
    #pragma unroll
    for (int hp = 0; hp < 32; ++hp) {
      const float E0 = __uint_as_float(ek[hp] << 16);
      const float E1 = __uint_as_float(ek[hp] & 0xffff0000u);
      const float* s = ar + hp * 8;                // uniform -> s_load_dwordx8
      a0 = fmaf(s[0], frcp(s[1] + E0), a0);
      a0 = fmaf(s[2], frcp(s[3] + E1), a0);
      a1 = fmaf(s[4], frcp(s[5] + E0), a1);
      a1 = fmaf(s[6], frcp(s[7] + E1), a1);
    }
    p[0][tid] = a0; p[1][tid] = a1;
  }
  __syncthreads();

  // ---- phase 2: masked softmax; wave = (query, quarter of K). 8 waves busy.
  const int qi = wave & 1, quarter = wave >> 1;
  const int kb2 = quarter * 128 + lane * 2;
  {
    float2 s = *(const float2*)&p[qi][kb2];        // garbage beyond vlen: masked
    s.x = (kb2     < vlen) ? s.x : NEG;
    s.y = (kb2 + 1 < vlen) ? s.y : NEG;
    float m = fmaxf(s.x, s.y);
    #pragma unroll
    for (int off = 32; off; off >>= 1) m = fmaxf(m, __shfl_xor(m, off, 64));
    if (lane == 0) red[qi][quarter][0] = m;
    __syncthreads();
    m = fmaxf(fmaxf(red[qi][0][0], red[qi][1][0]),
              fmaxf(red[qi][2][0], red[qi][3][0]));
    s.x = fexp2((s.x - m) * L2E);
    s.y = fexp2((s.y - m) * L2E);
    *(float2*)&p[qi][kb2] = s;                     // zeros beyond vlen
    float sum = s.x + s.y;
    #pragma unroll
    for (int off = 32; off; off >>= 1) sum += __shfl_xor(sum, off, 64);
    if (lane == 0) red[qi][quarter][1] = sum;
    __syncthreads();
  }

  // ---- phase 3: PV. wave covers keys [wave*64, wave*64+64), lane = v.
  {
    const int kb = wave * 64;
    if (kb < vlen) {
      const float* vb = values + ((size_t)b * K + kb) * V + lane;
      float a0 = 0.f, a1 = 0.f;
      #pragma unroll 4
      for (int k4 = 0; k4 < 64; k4 += 4) {
        const float4 p0 = *(const float4*)&p[0][kb + k4];  // uniform: broadcast
        const float4 p1 = *(const float4*)&p[1][kb + k4];
        const float v0 = vb[(size_t)(k4 + 0) * V];
        const float v1 = vb[(size_t)(k4 + 1) * V];
        const float v2 = vb[(size_t)(k4 + 2) * V];
        const float v3 = vb[(size_t)(k4 + 3) * V];
        a0 = fmaf(p0.x,v0, fmaf(p0.y,v1, fmaf(p0.z,v2, fmaf(p0.w,v3, a0))));
        a1 = fmaf(p1.x,v0, fmaf(p1.y,v1, fmaf(p1.z,v2, fmaf(p1.w,v3, a1))));
      }
      part[wave][0][lane] = a0; part[wave][1][lane] = a1;
    } else {
      part[wave][0][lane] = 0.f; part[wave][1][lane] = 0.f;
    }
  }
  __syncthreads();

  // ---- phase 4: cross-wave reduce + normalize + write (waves 0,1)
  if (wave < 2) {
    const float inv = frcp(red[wave][0][1] + red[wave][1][1] +
                           red[wave][2][1] + red[wave][3][1]);
    float o = 0.f;
    #pragma unroll
    for (int w = 0; w < 8; ++w) o += part[w][wave][lane];
    out[((size_t)b * Q + qg * 2 + wave) * V + lane] = o * inv;
  }
}

extern "C" void kernel_launch(void* const* d_in, const int* in_sizes, int n_in,
                              void* d_out, int out_size, void* d_ws, size_t ws_size,
                              hipStream_t stream) {
  const float* queries = (const float*)d_in[0];
  const float* keys    = (const float*)d_in[1];
  const float* values  = (const float*)d_in[2];
  const int*   vlens   = (const int*)d_in[3];
  const float* Wq      = (const float*)d_in[4];
  const float* Wk      = (const float*)d_in[5];
  const float* wv      = (const float*)d_in[6];
  float* out = (float*)d_out;

  float*    qAR2 = (float*)d_ws;                           // B*32*256 floats (1MB)
  unsigned* Ekp  = (unsigned*)(qAR2 + (size_t)B*32*256);   // B*32*512 dwords (2MB)

  proj_kernel<<<288, 256, 0, stream>>>(queries, keys, Wq, Wk, wv, vlens, qAR2, Ekp);
  attn_kernel<<<1024, 512, 0, stream>>>(qAR2, Ekp, values, vlens, out);
}